// Round 5
// baseline (131.157 us; speedup 1.0000x reference)
//
#include <hip/hip_runtime.h>

// DCN CrossLayer: B=16384, F=1024, L=3, fp32.
// Algebraic expansion (verified vs reference v1-v5):
//   d_j = x0 . w_j (per-row)     t01=b0.w1  t02=b0.w2  t12=b1.w2
//   a1 = 1+d0;  s1 = a1*d1 + t01;  a2 = a1+s1;  s2 = a2*d2 + t02+t12
//   out = x0*(a2+s2) + (b0+b1+b2)
//
// v6: back to the fused v1 structure (two-pass L3-reuse bet failed: pass2
// re-read x from HBM, split cost +3.2us). Change vs v1/v4: the use-once
// streams (x in, out out) go NONTEMPORAL. Evidence: kernel stuck at
// ~36.6us / 3.7 TB/s at mandatory traffic while fills hit 6.5 TB/s in the
// same window; v2 counters showed WRITE_SIZE 90MB vs 67 mandatory
// (write-allocate eviction churn). x is loaded once and out written once;
// cache allocation for either is pure overhead. w/bias (16 KiB broadcast,
// heavily reused) stay on the cached path.
// Single kernel, single launch: t-dots + bias_sum folded back per-wave
// (v1 vs v4 proved the hoist is worth ~0; the prep launch is not free).
// No forced launch-bounds min (v3 spill lesson). Live set ~60 VGPR.

constexpr int B = 16384;
constexpr int F = 1024;                 // 256 float4 per row = 4 chunks of 64 lanes
constexpr int WAVES = 4;
constexpr int ROWS_PER_BLOCK = WAVES;   // 1 row per wave
constexpr int BLOCK = 64 * WAVES;       // 256 threads

typedef float v4f __attribute__((ext_vector_type(4)));

__global__ __launch_bounds__(BLOCK) void cross_layer_kernel(
    const float* __restrict__ x,        // [B, F]
    const float* __restrict__ kernels,  // [3, F]
    const float* __restrict__ bias,     // [3, F]
    float* __restrict__ out)            // [B, F]
{
    const int lane = threadIdx.x & 63;
    const int wave = threadIdx.x >> 6;
    const int row  = blockIdx.x * ROWS_PER_BLOCK + wave;

    const v4f* xrow = (const v4f*)(x + (size_t)row * F);
    const v4f* w0v  = (const v4f*)(kernels);
    const v4f* w1v  = (const v4f*)(kernels + F);
    const v4f* w2v  = (const v4f*)(kernels + 2 * F);
    const v4f* b0v  = (const v4f*)(bias);
    const v4f* b1v  = (const v4f*)(bias + F);
    const v4f* b2v  = (const v4f*)(bias + 2 * F);

    // Front-load the x row, nontemporal (use-once stream; no cache alloc).
    v4f x0[4];
#pragma unroll
    for (int c = 0; c < 4; ++c)
        x0[c] = __builtin_nontemporal_load(&xrow[c * 64 + lane]);

    // 6 independent partial sums: d0,d1,d2 (x.w_j) and t01,t02,t12 (b.w_j).
    float p0 = 0.f, p1 = 0.f, p2 = 0.f, p3 = 0.f, p4 = 0.f, p5 = 0.f;
#pragma unroll
    for (int c = 0; c < 4; ++c) {
        const int i = c * 64 + lane;
        const v4f w0 = w0v[i];
        const v4f w1 = w1v[i];
        const v4f w2 = w2v[i];
        const v4f b0 = b0v[i];
        const v4f b1 = b1v[i];
        const v4f xv = x0[c];

        p0 = fmaf(xv.x, w0.x, p0); p0 = fmaf(xv.y, w0.y, p0);
        p0 = fmaf(xv.z, w0.z, p0); p0 = fmaf(xv.w, w0.w, p0);

        p1 = fmaf(xv.x, w1.x, p1); p1 = fmaf(xv.y, w1.y, p1);
        p1 = fmaf(xv.z, w1.z, p1); p1 = fmaf(xv.w, w1.w, p1);

        p2 = fmaf(xv.x, w2.x, p2); p2 = fmaf(xv.y, w2.y, p2);
        p2 = fmaf(xv.z, w2.z, p2); p2 = fmaf(xv.w, w2.w, p2);

        p3 = fmaf(b0.x, w1.x, p3); p3 = fmaf(b0.y, w1.y, p3);
        p3 = fmaf(b0.z, w1.z, p3); p3 = fmaf(b0.w, w1.w, p3);

        p4 = fmaf(b0.x, w2.x, p4); p4 = fmaf(b0.y, w2.y, p4);
        p4 = fmaf(b0.z, w2.z, p4); p4 = fmaf(b0.w, w2.w, p4);

        p5 = fmaf(b1.x, w2.x, p5); p5 = fmaf(b1.y, w2.y, p5);
        p5 = fmaf(b1.z, w2.z, p5); p5 = fmaf(b1.w, w2.w, p5);
    }

    // Single interleaved 6-value butterfly (shuffles per step independent).
#pragma unroll
    for (int off = 32; off >= 1; off >>= 1) {
        p0 += __shfl_xor(p0, off, 64);
        p1 += __shfl_xor(p1, off, 64);
        p2 += __shfl_xor(p2, off, 64);
        p3 += __shfl_xor(p3, off, 64);
        p4 += __shfl_xor(p4, off, 64);
        p5 += __shfl_xor(p5, off, 64);
    }

    // Scalar recurrence (all lanes hold the full sums).
    const float a1 = 1.f + p0;
    const float s1 = fmaf(a1, p1, p3);
    const float a2 = a1 + s1;
    const float s2 = fmaf(a2, p2, p4 + p5);
    const float S  = a2 + s2;

    // Epilogue: out = x0*S + (b0+b1+b2). b re-read from L1 (cached path);
    // out stores nontemporal (use-once stream; no write-allocate churn).
    v4f* orow = (v4f*)(out + (size_t)row * F);
#pragma unroll
    for (int c = 0; c < 4; ++c) {
        const int i = c * 64 + lane;
        const v4f b0 = b0v[i];
        const v4f b1 = b1v[i];
        const v4f b2 = b2v[i];
        v4f o;
        o.x = fmaf(x0[c].x, S, b0.x + b1.x + b2.x);
        o.y = fmaf(x0[c].y, S, b0.y + b1.y + b2.y);
        o.z = fmaf(x0[c].z, S, b0.z + b1.z + b2.z);
        o.w = fmaf(x0[c].w, S, b0.w + b1.w + b2.w);
        __builtin_nontemporal_store(o, &orow[i]);
    }
}

extern "C" void kernel_launch(void* const* d_in, const int* in_sizes, int n_in,
                              void* d_out, int out_size, void* d_ws, size_t ws_size,
                              hipStream_t stream) {
    const float* x       = (const float*)d_in[0];
    const float* kernels = (const float*)d_in[1];
    const float* bias    = (const float*)d_in[2];
    float* out           = (float*)d_out;

    dim3 grid(B / ROWS_PER_BLOCK);  // 4096 blocks
    dim3 block(BLOCK);              // 256 threads = 4 waves
    cross_layer_kernel<<<grid, block, 0, stream>>>(x, kernels, bias, out);
}

// Round 6
// 114.734 us; speedup vs baseline: 1.1431x; 1.1431x over previous
//
#include <hip/hip_runtime.h>

// DCN CrossLayer: B=16384, F=1024, L=3, fp32.
// Algebraic expansion (verified vs reference v1-v6):
//   d_j = x0 . w_j (per-row)     t01=b0.w1  t02=b0.w2  t12=b1.w2 (global)
//   a1 = 1+d0;  s1 = a1*d1 + t01;  a2 = a1+s1;  s2 = a2*d2 + t02+t12
//   out = x0*(a2+s2) + (b0+b1+b2)
//
// v7 = evidence-merged best of v1-v6:
//  - prep kernel hoists t-terms + bias_sum (v4: free, trims butterfly 6->3
//    per row and kills 20 b-loads/row).
//  - R=2 rows/wave IN REGISTERS, grid 2048x256 -> 8192 waves = exactly
//    32 waves/CU, full single-generation residency (v2's R=4 failure was
//    occupancy, not batching; R=2 keeps residency AND shares every w/bs
//    broadcast load across 2 rows: 16 mem inst/row).
//  - All 8 x float4 loads front-issued (deep MLP; wave never waits on
//    memory again after the initial drain), single merged 6-value
//    butterfly = half the serial DS chains of two 3-value ones.
//  - NT stores only (v6: WRITE_SIZE hit exactly 64 MiB -> churn gone;
//    NT LOADS were the regression - x reads stay on the cached path and
//    harvest the ~20 MB the poison fill leaves in L3).
//  - No forced __launch_bounds__ min (v3 spill lesson). Live set ~60 VGPR;
//    >64 here would drop to 4 waves/SIMD -> the go/no-go counter is
//    VGPR_Count.

constexpr int B = 16384;
constexpr int F = 1024;                 // 256 float4 per row
constexpr int WAVES = 4;
constexpr int RPW = 2;                  // rows per wave
constexpr int ROWS_PER_BLOCK = WAVES * RPW;  // 8
constexpr int BLOCK = 64 * WAVES;       // 256 threads

typedef float v4f __attribute__((ext_vector_type(4)));

// ---------------------------------------------------------------- prep ----
__global__ __launch_bounds__(BLOCK) void prep_kernel(
    const float* __restrict__ kernels,  // [3, F]
    const float* __restrict__ bias,     // [3, F]
    float* __restrict__ ws)             // [0..2]=t01,t02,t12  [4..1027]=bias_sum
{
    const int tid = threadIdx.x;
    const v4f* w1v = (const v4f*)(kernels + F);
    const v4f* w2v = (const v4f*)(kernels + 2 * F);
    const v4f* b0v = (const v4f*)(bias);
    const v4f* b1v = (const v4f*)(bias + F);
    const v4f* b2v = (const v4f*)(bias + 2 * F);

    // bias_sum: thread t owns float4 t (256 threads x float4 = 1024 floats).
    const v4f B0 = b0v[tid];
    const v4f B1 = b1v[tid];
    const v4f B2 = b2v[tid];
    v4f bs;
    bs.x = B0.x + B1.x + B2.x;
    bs.y = B0.y + B1.y + B2.y;
    bs.z = B0.z + B1.z + B2.z;
    bs.w = B0.w + B1.w + B2.w;
    ((v4f*)(ws + 4))[tid] = bs;

    if (tid < 64) {
        float t01 = 0.f, t02 = 0.f, t12 = 0.f;
#pragma unroll
        for (int c = 0; c < 4; ++c) {
            const int i = c * 64 + tid;
            const v4f w1 = w1v[i];
            const v4f w2 = w2v[i];
            const v4f b0 = b0v[i];
            const v4f b1 = b1v[i];
            t01 = fmaf(b0.x, w1.x, t01); t01 = fmaf(b0.y, w1.y, t01);
            t01 = fmaf(b0.z, w1.z, t01); t01 = fmaf(b0.w, w1.w, t01);
            t02 = fmaf(b0.x, w2.x, t02); t02 = fmaf(b0.y, w2.y, t02);
            t02 = fmaf(b0.z, w2.z, t02); t02 = fmaf(b0.w, w2.w, t02);
            t12 = fmaf(b1.x, w2.x, t12); t12 = fmaf(b1.y, w2.y, t12);
            t12 = fmaf(b1.z, w2.z, t12); t12 = fmaf(b1.w, w2.w, t12);
        }
#pragma unroll
        for (int off = 32; off >= 1; off >>= 1) {
            t01 += __shfl_xor(t01, off, 64);
            t02 += __shfl_xor(t02, off, 64);
            t12 += __shfl_xor(t12, off, 64);
        }
        if (tid == 0) { ws[0] = t01; ws[1] = t02; ws[2] = t12; }
    }
}

// ---------------------------------------------------------------- main ----
__global__ __launch_bounds__(BLOCK) void cross_layer_kernel(
    const float* __restrict__ x,        // [B, F]
    const float* __restrict__ kernels,  // [3, F]
    const float* __restrict__ ws,       // prep output
    float* __restrict__ out)            // [B, F]
{
    const int lane = threadIdx.x & 63;
    const int wave = threadIdx.x >> 6;
    const int row0 = blockIdx.x * ROWS_PER_BLOCK + wave * RPW;

    const v4f* w0v = (const v4f*)(kernels);
    const v4f* w1v = (const v4f*)(kernels + F);
    const v4f* w2v = (const v4f*)(kernels + 2 * F);
    const v4f* bsv = (const v4f*)(ws + 4);

    // Front-issue all 8 x loads (cached path: harvest L3 leftovers).
    v4f xr[RPW][4];
#pragma unroll
    for (int r = 0; r < RPW; ++r) {
        const v4f* xrow = (const v4f*)(x + (size_t)(row0 + r) * F);
#pragma unroll
        for (int c = 0; c < 4; ++c) xr[r][c] = xrow[c * 64 + lane];
    }

    // Uniform scalars from prep.
    const float t01  = ws[0];
    const float tsum = ws[1] + ws[2];

    // 6 per-row dot partials; each w load shared by both rows.
    float d00 = 0.f, d01 = 0.f, d02 = 0.f;
    float d10 = 0.f, d11 = 0.f, d12 = 0.f;
#pragma unroll
    for (int c = 0; c < 4; ++c) {
        const int i = c * 64 + lane;
        const v4f w0 = w0v[i];
        const v4f w1 = w1v[i];
        const v4f w2 = w2v[i];
        const v4f a = xr[0][c];
        const v4f b = xr[1][c];
        d00 = fmaf(a.x, w0.x, d00); d00 = fmaf(a.y, w0.y, d00);
        d00 = fmaf(a.z, w0.z, d00); d00 = fmaf(a.w, w0.w, d00);
        d01 = fmaf(a.x, w1.x, d01); d01 = fmaf(a.y, w1.y, d01);
        d01 = fmaf(a.z, w1.z, d01); d01 = fmaf(a.w, w1.w, d01);
        d02 = fmaf(a.x, w2.x, d02); d02 = fmaf(a.y, w2.y, d02);
        d02 = fmaf(a.z, w2.z, d02); d02 = fmaf(a.w, w2.w, d02);
        d10 = fmaf(b.x, w0.x, d10); d10 = fmaf(b.y, w0.y, d10);
        d10 = fmaf(b.z, w0.z, d10); d10 = fmaf(b.w, w0.w, d10);
        d11 = fmaf(b.x, w1.x, d11); d11 = fmaf(b.y, w1.y, d11);
        d11 = fmaf(b.z, w1.z, d11); d11 = fmaf(b.w, w1.w, d11);
        d12 = fmaf(b.x, w2.x, d12); d12 = fmaf(b.y, w2.y, d12);
        d12 = fmaf(b.z, w2.z, d12); d12 = fmaf(b.w, w2.w, d12);
    }

    // Single merged 6-value butterfly (one serial DS chain for both rows).
#pragma unroll
    for (int off = 32; off >= 1; off >>= 1) {
        d00 += __shfl_xor(d00, off, 64);
        d01 += __shfl_xor(d01, off, 64);
        d02 += __shfl_xor(d02, off, 64);
        d10 += __shfl_xor(d10, off, 64);
        d11 += __shfl_xor(d11, off, 64);
        d12 += __shfl_xor(d12, off, 64);
    }

    // Scalar recurrences.
    float S0, S1;
    {
        const float a1 = 1.f + d00;
        const float s1 = fmaf(a1, d01, t01);
        const float a2 = a1 + s1;
        const float s2 = fmaf(a2, d02, tsum);
        S0 = a2 + s2;
    }
    {
        const float a1 = 1.f + d10;
        const float s1 = fmaf(a1, d11, t01);
        const float a2 = a1 + s1;
        const float s2 = fmaf(a2, d12, tsum);
        S1 = a2 + s2;
    }

    // Epilogue: out = x*S + bias_sum; bs load shared by both rows;
    // NT stores (proven: WRITE_SIZE drops to exactly 64 MiB).
    v4f* orow0 = (v4f*)(out + (size_t)row0 * F);
    v4f* orow1 = (v4f*)(out + (size_t)(row0 + 1) * F);
#pragma unroll
    for (int c = 0; c < 4; ++c) {
        const int i = c * 64 + lane;
        const v4f bs = bsv[i];
        v4f o0, o1;
        o0.x = fmaf(xr[0][c].x, S0, bs.x);
        o0.y = fmaf(xr[0][c].y, S0, bs.y);
        o0.z = fmaf(xr[0][c].z, S0, bs.z);
        o0.w = fmaf(xr[0][c].w, S0, bs.w);
        o1.x = fmaf(xr[1][c].x, S1, bs.x);
        o1.y = fmaf(xr[1][c].y, S1, bs.y);
        o1.z = fmaf(xr[1][c].z, S1, bs.z);
        o1.w = fmaf(xr[1][c].w, S1, bs.w);
        __builtin_nontemporal_store(o0, &orow0[i]);
        __builtin_nontemporal_store(o1, &orow1[i]);
    }
}

extern "C" void kernel_launch(void* const* d_in, const int* in_sizes, int n_in,
                              void* d_out, int out_size, void* d_ws, size_t ws_size,
                              hipStream_t stream) {
    const float* x       = (const float*)d_in[0];
    const float* kernels = (const float*)d_in[1];
    const float* bias    = (const float*)d_in[2];
    float* out           = (float*)d_out;
    float* ws            = (float*)d_ws;   // needs 1028 floats (~4.1 KiB)

    prep_kernel<<<dim3(1), dim3(BLOCK), 0, stream>>>(kernels, bias, ws);
    cross_layer_kernel<<<dim3(B / ROWS_PER_BLOCK), dim3(BLOCK), 0, stream>>>(
        x, kernels, ws, out);
}

// Round 7
// 111.959 us; speedup vs baseline: 1.1715x; 1.0248x over previous
//
#include <hip/hip_runtime.h>

// DCN CrossLayer: B=16384, F=1024, L=3, fp32.
// Algebraic expansion (verified vs reference v1-v7):
//   d_j = x0 . w_j (per-row)     t01=b0.w1  t02=b0.w2  t12=b1.w2 (global)
//   a1 = 1+d0;  s1 = a1*d1 + t01;  a2 = a1+s1;  s2 = a2*d2 + t02+t12
//   out = x0*(a2+s2) + (b0+b1+b2)
//
// v8 = v7 minus the prep launch. v7's kernel region (~30.5us) still paid
// ~4-5us for the 1-block prep kernel + graph-node serialization (evidence:
// v1 vs v4 showed prep's per-row savings were almost exactly cancelled by
// its overhead). v8 amortizes the shared work PER BLOCK instead:
//   waves 2,3 : bias_sum = b0+b1+b2 -> LDS (L1-hot loads, done while
//               waves 0,1 are still in their dot loops)
//   wave 0    : t01,t02 partials folded into its own butterfly (8 values)
//   wave 1    : t12 partial folded in (7 values)
//   one __syncthreads publishes t* via LDS; epilogue reads bias_sum from
//   LDS (4 ds_read_b128/wave instead of 12 global loads).
// Everything else is v7 verbatim: R=2 rows/wave in registers, 2048 blocks
// = exactly 32 waves/CU full residency, all 8 x-loads front-issued, merged
// butterfly, NT stores only (WRITE_SIZE proven to hit exactly 64 MiB),
// cached x loads (NT loads proven regression), no forced launch-bounds
// min (v3 spill lesson). Live-set target <= 72 VGPR.

constexpr int B = 16384;
constexpr int F = 1024;                 // 256 float4 per row
constexpr int WAVES = 4;
constexpr int RPW = 2;                  // rows per wave
constexpr int ROWS_PER_BLOCK = WAVES * RPW;  // 8
constexpr int BLOCK = 64 * WAVES;       // 256 threads

typedef float v4f __attribute__((ext_vector_type(4)));

__global__ __launch_bounds__(BLOCK) void cross_layer_kernel(
    const float* __restrict__ x,        // [B, F]
    const float* __restrict__ kernels,  // [3, F]
    const float* __restrict__ bias,     // [3, F]
    float* __restrict__ out)            // [B, F]
{
    __shared__ v4f   bs_lds[F / 4];     // bias_sum, 256 x float4 = 4 KiB
    __shared__ float t_lds[3];          // t01, t02, t12

    const int lane = threadIdx.x & 63;
    const int wave = threadIdx.x >> 6;
    const int row0 = blockIdx.x * ROWS_PER_BLOCK + wave * RPW;

    const v4f* w0v = (const v4f*)(kernels);
    const v4f* w1v = (const v4f*)(kernels + F);
    const v4f* w2v = (const v4f*)(kernels + 2 * F);
    const v4f* b0v = (const v4f*)(bias);
    const v4f* b1v = (const v4f*)(bias + F);
    const v4f* b2v = (const v4f*)(bias + 2 * F);

    // Front-issue all 8 x loads (cached path).
    v4f xr[RPW][4];
#pragma unroll
    for (int r = 0; r < RPW; ++r) {
        const v4f* xrow = (const v4f*)(x + (size_t)(row0 + r) * F);
#pragma unroll
        for (int c = 0; c < 4; ++c) xr[r][c] = xrow[c * 64 + lane];
    }

    // Waves 2,3: block-shared bias_sum into LDS (b loads are L1-hot after
    // the first block on each CU; 6 loads + 2 LDS writes per thread).
    if (wave >= 2) {
        const int t2 = threadIdx.x - 128;           // 0..127
#pragma unroll
        for (int k = 0; k < 2; ++k) {
            const int i = t2 + k * 128;             // covers 0..255
            bs_lds[i] = b0v[i] + b1v[i] + b2v[i];
        }
    }

    // Per-row dot partials; each w load shared by both rows.
    float d00 = 0.f, d01 = 0.f, d02 = 0.f;
    float d10 = 0.f, d11 = 0.f, d12 = 0.f;
#pragma unroll
    for (int c = 0; c < 4; ++c) {
        const int i = c * 64 + lane;
        const v4f w0 = w0v[i];
        const v4f w1 = w1v[i];
        const v4f w2 = w2v[i];
        const v4f a = xr[0][c];
        const v4f b = xr[1][c];
        d00 = fmaf(a.x, w0.x, d00); d00 = fmaf(a.y, w0.y, d00);
        d00 = fmaf(a.z, w0.z, d00); d00 = fmaf(a.w, w0.w, d00);
        d01 = fmaf(a.x, w1.x, d01); d01 = fmaf(a.y, w1.y, d01);
        d01 = fmaf(a.z, w1.z, d01); d01 = fmaf(a.w, w1.w, d01);
        d02 = fmaf(a.x, w2.x, d02); d02 = fmaf(a.y, w2.y, d02);
        d02 = fmaf(a.z, w2.z, d02); d02 = fmaf(a.w, w2.w, d02);
        d10 = fmaf(b.x, w0.x, d10); d10 = fmaf(b.y, w0.y, d10);
        d10 = fmaf(b.z, w0.z, d10); d10 = fmaf(b.w, w0.w, d10);
        d11 = fmaf(b.x, w1.x, d11); d11 = fmaf(b.y, w1.y, d11);
        d11 = fmaf(b.z, w1.z, d11); d11 = fmaf(b.w, w1.w, d11);
        d12 = fmaf(b.x, w2.x, d12); d12 = fmaf(b.y, w2.y, d12);
        d12 = fmaf(b.z, w2.z, d12); d12 = fmaf(b.w, w2.w, d12);
    }

    // t-dot partials (L1-hot re-reads; separate loop keeps the main dot
    // loop's scheduling clean).
    float e0 = 0.f, e1 = 0.f;
    if (wave == 0) {
#pragma unroll
        for (int c = 0; c < 4; ++c) {
            const int i = c * 64 + lane;
            const v4f b0 = b0v[i];
            const v4f w1 = w1v[i];
            const v4f w2 = w2v[i];
            e0 = fmaf(b0.x, w1.x, e0); e0 = fmaf(b0.y, w1.y, e0);
            e0 = fmaf(b0.z, w1.z, e0); e0 = fmaf(b0.w, w1.w, e0);
            e1 = fmaf(b0.x, w2.x, e1); e1 = fmaf(b0.y, w2.y, e1);
            e1 = fmaf(b0.z, w2.z, e1); e1 = fmaf(b0.w, w2.w, e1);
        }
    } else if (wave == 1) {
#pragma unroll
        for (int c = 0; c < 4; ++c) {
            const int i = c * 64 + lane;
            const v4f b1 = b1v[i];
            const v4f w2 = w2v[i];
            e0 = fmaf(b1.x, w2.x, e0); e0 = fmaf(b1.y, w2.y, e0);
            e0 = fmaf(b1.z, w2.z, e0); e0 = fmaf(b1.w, w2.w, e0);
        }
    }

    // Merged butterfly (wave-uniform variant selection).
    if (wave == 0) {
#pragma unroll
        for (int off = 32; off >= 1; off >>= 1) {
            d00 += __shfl_xor(d00, off, 64);
            d01 += __shfl_xor(d01, off, 64);
            d02 += __shfl_xor(d02, off, 64);
            d10 += __shfl_xor(d10, off, 64);
            d11 += __shfl_xor(d11, off, 64);
            d12 += __shfl_xor(d12, off, 64);
            e0  += __shfl_xor(e0,  off, 64);
            e1  += __shfl_xor(e1,  off, 64);
        }
        if (lane == 0) { t_lds[0] = e0; t_lds[1] = e1; }
    } else if (wave == 1) {
#pragma unroll
        for (int off = 32; off >= 1; off >>= 1) {
            d00 += __shfl_xor(d00, off, 64);
            d01 += __shfl_xor(d01, off, 64);
            d02 += __shfl_xor(d02, off, 64);
            d10 += __shfl_xor(d10, off, 64);
            d11 += __shfl_xor(d11, off, 64);
            d12 += __shfl_xor(d12, off, 64);
            e0  += __shfl_xor(e0,  off, 64);
        }
        if (lane == 0) { t_lds[2] = e0; }
    } else {
#pragma unroll
        for (int off = 32; off >= 1; off >>= 1) {
            d00 += __shfl_xor(d00, off, 64);
            d01 += __shfl_xor(d01, off, 64);
            d02 += __shfl_xor(d02, off, 64);
            d10 += __shfl_xor(d10, off, 64);
            d11 += __shfl_xor(d11, off, 64);
            d12 += __shfl_xor(d12, off, 64);
        }
    }

    __syncthreads();
    const float t01  = t_lds[0];
    const float tsum = t_lds[1] + t_lds[2];

    // Scalar recurrences.
    float S0, S1;
    {
        const float a1 = 1.f + d00;
        const float s1 = fmaf(a1, d01, t01);
        const float a2 = a1 + s1;
        const float s2 = fmaf(a2, d02, tsum);
        S0 = a2 + s2;
    }
    {
        const float a1 = 1.f + d10;
        const float s1 = fmaf(a1, d11, t01);
        const float a2 = a1 + s1;
        const float s2 = fmaf(a2, d12, tsum);
        S1 = a2 + s2;
    }

    // Epilogue: out = x*S + bias_sum (from LDS); NT stores.
    v4f* orow0 = (v4f*)(out + (size_t)row0 * F);
    v4f* orow1 = (v4f*)(out + (size_t)(row0 + 1) * F);
#pragma unroll
    for (int c = 0; c < 4; ++c) {
        const int i = c * 64 + lane;
        const v4f bs = bs_lds[i];
        v4f o0, o1;
        o0.x = fmaf(xr[0][c].x, S0, bs.x);
        o0.y = fmaf(xr[0][c].y, S0, bs.y);
        o0.z = fmaf(xr[0][c].z, S0, bs.z);
        o0.w = fmaf(xr[0][c].w, S0, bs.w);
        o1.x = fmaf(xr[1][c].x, S1, bs.x);
        o1.y = fmaf(xr[1][c].y, S1, bs.y);
        o1.z = fmaf(xr[1][c].z, S1, bs.z);
        o1.w = fmaf(xr[1][c].w, S1, bs.w);
        __builtin_nontemporal_store(o0, &orow0[i]);
        __builtin_nontemporal_store(o1, &orow1[i]);
    }
}

extern "C" void kernel_launch(void* const* d_in, const int* in_sizes, int n_in,
                              void* d_out, int out_size, void* d_ws, size_t ws_size,
                              hipStream_t stream) {
    const float* x       = (const float*)d_in[0];
    const float* kernels = (const float*)d_in[1];
    const float* bias    = (const float*)d_in[2];
    float* out           = (float*)d_out;

    cross_layer_kernel<<<dim3(B / ROWS_PER_BLOCK), dim3(BLOCK), 0, stream>>>(
        x, kernels, bias, out);
}